// Round 7
// baseline (24981.488 us; speedup 1.0000x reference)
//
#include <hip/hip_runtime.h>
#include <hip/hip_fp16.h>
#include <math.h>

#define NN 50000
#define NE 600000
#define H 128
#define TWO_H 256
#define THREE_H 384
#define NLAYER 10

__device__ __forceinline__ float gelu_f(float x) {
    return 0.5f * x * (1.0f + erff(x * 0.70710678118654752f));
}

__device__ __forceinline__ float wave_reduce_add64(float v) {
#pragma unroll
    for (int m = 32; m >= 1; m >>= 1) v += __shfl_xor(v, m);
    return v;
}

// ---- typed 4-element load/store helpers over a void* state buffer ----
template <bool HALF>
__device__ __forceinline__ float4 buf_load4(const void* p, size_t off) {
    if constexpr (HALF) {
        const __half2* q = (const __half2*)((const __half*)p + off);
        float2 a = __half22float2(q[0]);
        float2 b = __half22float2(q[1]);
        return make_float4(a.x, a.y, b.x, b.y);
    } else {
        return *(const float4*)((const float*)p + off);
    }
}
template <bool HALF>
__device__ __forceinline__ void buf_store4(void* p, size_t off, float4 v) {
    if constexpr (HALF) {
        __half2* q = (__half2*)((__half*)p + off);
        q[0] = __floats2half2_rn(v.x, v.y);
        q[1] = __floats2half2_rn(v.z, v.w);
    } else {
        *(float4*)((float*)p + off) = v;
    }
}

__global__ void signal_kernel(float* __restrict__ out, int n, float val) {
    int i = blockIdx.x * blockDim.x + threadIdx.x;
    if (i < n) out[i] = val;
}

// ---------------- encoder: h = GELU(LN(x @ enc_w + enc_b)) ----------------
__global__ __launch_bounds__(128) void encoder_kernel(
    const float* __restrict__ x, const float* __restrict__ w,
    const float* __restrict__ b, const float* __restrict__ g,
    const float* __restrict__ bb, float* __restrict__ h) {
    int n = blockIdx.x;
    int j = threadIdx.x;
    __shared__ float xs[3];
    __shared__ float2 red[2];
    if (j < 3) xs[j] = x[n * 3 + j];
    __syncthreads();
    float v = b[j] + xs[0] * w[j] + xs[1] * w[H + j] + xs[2] * w[2 * H + j];
    float s = v, sq = v * v;
    s = wave_reduce_add64(s);
    sq = wave_reduce_add64(sq);
    if ((j & 63) == 0) red[j >> 6] = make_float2(s, sq);
    __syncthreads();
    float ts = red[0].x + red[1].x;
    float tq = red[0].y + red[1].y;
    float m = ts * (1.0f / 128.0f);
    float var = tq * (1.0f / 128.0f) - m * m;
    float rs = rsqrtf(var + 1e-5f);
    h[(size_t)n * H + j] = gelu_f((v - m) * rs * g[j] + bb[j]);
}

// ---------------- edge encoder: ea = edge_attr @ eenc_w + eenc_b (fp16 out) ----------------
__global__ __launch_bounds__(128) void eenc_kernel(
    const float* __restrict__ attr, const float* __restrict__ w,
    const float* __restrict__ b, __half* __restrict__ ea) {
    int e = blockIdx.x;
    int j = threadIdx.x;
    __shared__ float as_[8];
    if (j < 8) as_[j] = attr[(size_t)e * 8 + j];
    __syncthreads();
    float v = b[j];
#pragma unroll
    for (int k = 0; k < 8; k++) v += as_[k] * w[k * H + j];
    ea[(size_t)e * H + j] = __float2half_rn(v);
}

// ---------------- degree count ----------------
__global__ void count_kernel(const int* __restrict__ col, int* __restrict__ cnt) {
    int i = blockIdx.x * blockDim.x + threadIdx.x;
    if (i < NE) atomicAdd(&cnt[col[i]], 1);
}

// ---------------- exclusive scan (single block) ----------------
__global__ __launch_bounds__(1024) void scan_kernel(
    const int* __restrict__ cnt, int* __restrict__ rstart, float* __restrict__ cntf) {
    __shared__ int buf[1024];
    __shared__ int s_carry;
    int tid = threadIdx.x;
    if (tid == 0) s_carry = 0;
    __syncthreads();
    for (int base = 0; base < NN; base += 1024) {
        int i = base + tid;
        int v = (i < NN) ? cnt[i] : 0;
        buf[tid] = v;
        __syncthreads();
        for (int off = 1; off < 1024; off <<= 1) {
            int add = (tid >= off) ? buf[tid - off] : 0;
            __syncthreads();
            buf[tid] += add;
            __syncthreads();
        }
        int incl = buf[tid];
        int cv = s_carry;
        if (i < NN) {
            rstart[i] = cv + incl - v;
            cntf[i] = (float)(v > 1 ? v : 1);
        }
        __syncthreads();
        if (tid == 0) s_carry = cv + buf[1023];
        __syncthreads();
    }
    if (threadIdx.x == 0) rstart[NN] = s_carry;
}

__global__ void init_fill_kernel(const int* __restrict__ rstart, int* __restrict__ fptr) {
    int i = blockIdx.x * blockDim.x + threadIdx.x;
    if (i < NN) fptr[i] = rstart[i];
}

__global__ void fill_kernel(const int* __restrict__ col, int* __restrict__ fptr,
                            int* __restrict__ elist) {
    int i = blockIdx.x * blockDim.x + threadIdx.x;
    if (i < NE) {
        int c = col[i];
        int p = atomicAdd(&fptr[c], 1);
        elist[p] = i;
    }
}

// ---------------- CSR mean aggregation (fp16 ea -> fp32 agg) ----------------
__global__ __launch_bounds__(128) void aggregate_kernel(
    const __half* __restrict__ ea, const int* __restrict__ elist,
    const int* __restrict__ rstart, const float* __restrict__ cntf,
    float* __restrict__ agg) {
    int n = blockIdx.x;
    int t = threadIdx.x;
    int s = rstart[n], e_end = rstart[n + 1];
    float sum = 0.0f;
    for (int p = s; p < e_end; ++p) {
        int e = elist[p];
        sum += __half2float(ea[(size_t)e * H + t]);
    }
    agg[(size_t)n * H + t] = sum / cntf[n];
}

// ---------------- fused MLP: resid += LN2(GELU(LN1(in @ w1 + b1)) @ w2 + b2) ----------------
// EDGE: in = [h[row] | h[col] | ea]  (K=384), resid = ea (fp16)
// NODE: in = [h[n]   | agg[n]]       (K=256), resid = h (fp32)
// LDS union (49.4 KB): GEMM1 phase {As[32*33] | Bs1[32*256]}, then {zs[32*258] | Bs2[32*128]}.
template <bool EDGE>
__global__ __launch_bounds__(256, 3) void mlp_fused(
    const float* h, const __half* ea,
    const float* agg, const int* __restrict__ eidx,
    const float* __restrict__ w1, const float* __restrict__ b1,
    const float* __restrict__ g1, const float* __restrict__ bb1,
    const float* __restrict__ w2, const float* __restrict__ b2,
    const float* __restrict__ g2, const float* __restrict__ bb2,
    void* resid, int nrows) {
    __shared__ float U[12352];
    __shared__ int rows_s[32], cols_s[32];
    float* As = U;           // [32k][33] (GEMM1)
    float* Bs1 = U + 1056;   // [32][256] (GEMM1)
    float* zs = U;           // [32][258] (LN1/GEMM2); aliases As/Bs1, z is in regs across switch
    float* Bs2 = U + 8256;   // [32][128] (GEMM2)

    const int t = threadIdx.x;
    const int e0 = blockIdx.x * 32;
    const int tx = t & 63, ty = t >> 6;    // GEMM1: cols 4*tx, rows 8*ty..+7
    const int tx2 = t & 31, ty2 = t >> 5;  // GEMM2: cols 4*tx2, rows 4*ty2..+3
    const int KIN = EDGE ? THREE_H : TWO_H;

    if (EDGE) {
        if (t < 32) rows_s[t] = eidx[e0 + t];
        else if (t < 64) cols_s[t - 32] = eidx[NE + e0 + t - 32];
    }

    // ---------- GEMM1: z = in @ w1 ----------
    float acc[8][4];
#pragma unroll
    for (int j = 0; j < 8; j++)
#pragma unroll
        for (int i = 0; i < 4; i++) acc[j][i] = 0.0f;

    for (int kb = 0; kb < KIN; kb += 32) {
        __syncthreads();
        {   // stage A chunk (gather), transposed to k-major
            int e = t >> 3;
            int kl = 4 * (t & 7);
            int k = kb + kl;
            float4 v;
            if (EDGE) {
                if (k < H) v = *(const float4*)(h + (size_t)rows_s[e] * H + k);
                else if (k < 2 * H) v = *(const float4*)(h + (size_t)cols_s[e] * H + (k - H));
                else v = buf_load4<true>(ea, (size_t)(e0 + e) * H + (k - 2 * H));
            } else {
                int n = e0 + e;
                if (n >= nrows) n = nrows - 1;
                v = (k < H) ? *(const float4*)(h + (size_t)n * H + k)
                            : *(const float4*)(agg + (size_t)n * H + (k - H));
            }
            As[(kl + 0) * 33 + e] = v.x;
            As[(kl + 1) * 33 + e] = v.y;
            As[(kl + 2) * 33 + e] = v.z;
            As[(kl + 3) * 33 + e] = v.w;
        }
        {   // stage B chunk: 32 rows x 256 cols
            const float* wsrc = w1 + (size_t)kb * 256;
#pragma unroll
            for (int p = 0; p < 8; p++) {
                int idx = p * 1024 + 4 * t;
                *(float4*)&Bs1[idx] = *(const float4*)(wsrc + idx);
            }
        }
        __syncthreads();
#pragma unroll 8
        for (int kk = 0; kk < 32; kk++) {
            float4 bv = *(const float4*)&Bs1[kk * 256 + 4 * tx];
#pragma unroll
            for (int j = 0; j < 8; j++) {
                float a = As[kk * 33 + 8 * ty + j];
                acc[j][0] += a * bv.x;
                acc[j][1] += a * bv.y;
                acc[j][2] += a * bv.z;
                acc[j][3] += a * bv.w;
            }
        }
    }
    __syncthreads();  // As/Bs1 dead; z lives in acc regs. Safe to write zs over them.
    {
        float4 bv = *(const float4*)(b1 + 4 * tx);
#pragma unroll
        for (int j = 0; j < 8; j++) {
            int e = 8 * ty + j;
            float2 lo = make_float2(acc[j][0] + bv.x, acc[j][1] + bv.y);
            float2 hi = make_float2(acc[j][2] + bv.z, acc[j][3] + bv.w);
            *(float2*)&zs[e * 258 + 4 * tx] = lo;
            *(float2*)&zs[e * 258 + 4 * tx + 2] = hi;
        }
    }
    __syncthreads();
    // LN1 over 256 + GELU (8 threads per row; groups of 8 never cross a wave)
    {
        int te = t >> 3, tl = t & 7;
        float vals[32];
        float s = 0.0f, sq = 0.0f;
#pragma unroll
        for (int i = 0; i < 32; i++) {
            float v = zs[te * 258 + tl * 32 + i];
            vals[i] = v;
            s += v;
            sq += v * v;
        }
        s += __shfl_xor(s, 1); s += __shfl_xor(s, 2); s += __shfl_xor(s, 4);
        sq += __shfl_xor(sq, 1); sq += __shfl_xor(sq, 2); sq += __shfl_xor(sq, 4);
        float m = s * (1.0f / 256.0f);
        float var = sq * (1.0f / 256.0f) - m * m;
        float rs = rsqrtf(var + 1e-5f);
#pragma unroll
        for (int i = 0; i < 32; i++) {
            int c = tl * 32 + i;
            float v = (vals[i] - m) * rs * g1[c] + bb1[c];
            zs[te * 258 + c] = gelu_f(v);
        }
    }
    __syncthreads();

    // ---------- GEMM2: d = zact @ w2 ----------
    float acc2[4][4];
#pragma unroll
    for (int j = 0; j < 4; j++)
#pragma unroll
        for (int i = 0; i < 4; i++) acc2[j][i] = 0.0f;

    for (int kb = 0; kb < TWO_H; kb += 32) {
        __syncthreads();
        {
            const float* wsrc = w2 + (size_t)kb * 128;
#pragma unroll
            for (int p = 0; p < 4; p++) {
                int idx = p * 1024 + 4 * t;
                *(float4*)&Bs2[idx] = *(const float4*)(wsrc + idx);
            }
        }
        __syncthreads();
#pragma unroll 8
        for (int kk = 0; kk < 32; kk++) {
            float4 bv = *(const float4*)&Bs2[kk * 128 + 4 * tx2];
#pragma unroll
            for (int j = 0; j < 4; j++) {
                float a = zs[(4 * ty2 + j) * 258 + kb + kk];
                acc2[j][0] += a * bv.x;
                acc2[j][1] += a * bv.y;
                acc2[j][2] += a * bv.z;
                acc2[j][3] += a * bv.w;
            }
        }
    }
    __syncthreads();  // all zs reads done; safe to alias dbuf onto U
    float* dbuf = U;  // [32][132]
    {
        float4 bv = *(const float4*)(b2 + 4 * tx2);
#pragma unroll
        for (int j = 0; j < 4; j++) {
            int e = 4 * ty2 + j;
            float4 o = make_float4(acc2[j][0] + bv.x, acc2[j][1] + bv.y,
                                   acc2[j][2] + bv.z, acc2[j][3] + bv.w);
            *(float4*)&dbuf[e * 132 + 4 * tx2] = o;
        }
    }
    __syncthreads();
    // LN2 over 128 + residual add
    {
        int te = t >> 3, tl = t & 7;
        float vals[16];
        float s = 0.0f, sq = 0.0f;
#pragma unroll
        for (int i = 0; i < 16; i++) {
            float v = dbuf[te * 132 + tl * 16 + i];
            vals[i] = v;
            s += v;
            sq += v * v;
        }
        s += __shfl_xor(s, 1); s += __shfl_xor(s, 2); s += __shfl_xor(s, 4);
        sq += __shfl_xor(sq, 1); sq += __shfl_xor(sq, 2); sq += __shfl_xor(sq, 4);
        float m = s * (1.0f / 128.0f);
        float var = sq * (1.0f / 128.0f) - m * m;
        float rs = rsqrtf(var + 1e-5f);
        bool valid = EDGE || (e0 + te < nrows);
        if (valid) {
            size_t base = (size_t)(e0 + te) * H + tl * 16;
#pragma unroll
            for (int q = 0; q < 4; q++) {
                int c0 = tl * 16 + q * 4;
                float4 o = buf_load4<EDGE>(resid, base + q * 4);
                o.x += (vals[q * 4 + 0] - m) * rs * g2[c0 + 0] + bb2[c0 + 0];
                o.y += (vals[q * 4 + 1] - m) * rs * g2[c0 + 1] + bb2[c0 + 1];
                o.z += (vals[q * 4 + 2] - m) * rs * g2[c0 + 2] + bb2[c0 + 2];
                o.w += (vals[q * 4 + 3] - m) * rs * g2[c0 + 3] + bb2[c0 + 3];
                buf_store4<EDGE>(resid, base + q * 4, o);
            }
        }
    }
}

// ---------------- decoder: out = GELU(h @ w1 + b1) @ w2 + b2 ----------------
__global__ __launch_bounds__(128) void decoder_kernel(
    const float* __restrict__ h, const float* __restrict__ w1,
    const float* __restrict__ b1, const float* __restrict__ w2,
    const float* __restrict__ b2, float* __restrict__ out) {
    int n = blockIdx.x;
    int j = threadIdx.x;
    __shared__ float hs[128];
    __shared__ float4 red[2];
    hs[j] = h[(size_t)n * H + j];
    __syncthreads();
    float t1 = b1[j];
#pragma unroll 8
    for (int k = 0; k < 128; k++) t1 += hs[k] * w1[k * H + j];
    t1 = gelu_f(t1);
    float4 w = *(const float4*)(w2 + j * 4);
    float4 p = make_float4(t1 * w.x, t1 * w.y, t1 * w.z, t1 * w.w);
#pragma unroll
    for (int m = 32; m >= 1; m >>= 1) {
        p.x += __shfl_xor(p.x, m);
        p.y += __shfl_xor(p.y, m);
        p.z += __shfl_xor(p.z, m);
        p.w += __shfl_xor(p.w, m);
    }
    if ((j & 63) == 0) red[j >> 6] = p;
    __syncthreads();
    if (j == 0) {
        out[(size_t)n * 4 + 0] = red[0].x + red[1].x + b2[0];
        out[(size_t)n * 4 + 1] = red[0].y + red[1].y + b2[1];
        out[(size_t)n * 4 + 2] = red[0].z + red[1].z + b2[2];
        out[(size_t)n * 4 + 3] = red[0].w + red[1].w + b2[3];
    }
}

extern "C" void kernel_launch(void* const* d_in, const int* in_sizes, int n_in,
                              void* d_out, int out_size, void* d_ws, size_t ws_size,
                              hipStream_t stream) {
    const float* x = (const float*)d_in[0];
    const int* eidx = (const int*)d_in[1];
    const float* eattr = (const float*)d_in[2];
    const float* enc_w = (const float*)d_in[3];
    const float* enc_b = (const float*)d_in[4];
    const float* enc_g = (const float*)d_in[5];
    const float* enc_bb = (const float*)d_in[6];
    const float* eenc_w = (const float*)d_in[7];
    const float* eenc_b = (const float*)d_in[8];
    const float* e_w1 = (const float*)d_in[9];
    const float* e_b1 = (const float*)d_in[10];
    const float* e_g1 = (const float*)d_in[11];
    const float* e_bb1 = (const float*)d_in[12];
    const float* e_w2 = (const float*)d_in[13];
    const float* e_b2 = (const float*)d_in[14];
    const float* e_g2 = (const float*)d_in[15];
    const float* e_bb2 = (const float*)d_in[16];
    const float* n_w1 = (const float*)d_in[17];
    const float* n_b1 = (const float*)d_in[18];
    const float* n_g1 = (const float*)d_in[19];
    const float* n_bb1 = (const float*)d_in[20];
    const float* n_w2 = (const float*)d_in[21];
    const float* n_b2 = (const float*)d_in[22];
    const float* n_g2 = (const float*)d_in[23];
    const float* n_bb2 = (const float*)d_in[24];
    const float* dec_w1 = (const float*)d_in[25];
    const float* dec_b1 = (const float*)d_in[26];
    const float* dec_w2 = (const float*)d_in[27];
    const float* dec_b2 = (const float*)d_in[28];
    float* out = (float*)d_out;
    (void)in_sizes; (void)n_in;

    auto AL = [](size_t b) { return (b + 255) & ~(size_t)255; };
    const size_t need = AL((size_t)NN * H * 4)      // h (fp32)
                      + AL((size_t)NE * H * 2)      // ea (fp16)
                      + AL((size_t)NN * H * 4)      // agg (fp32)
                      + AL((size_t)NN * 4)          // cntf
                      + AL((size_t)NN * 4)          // cnt
                      + AL((size_t)(NN + 1) * 4)    // rstart
                      + AL((size_t)NN * 4)          // fptr
                      + AL((size_t)NE * 4);         // elist

    if (ws_size < need) {
        // Diagnostic: absmax error will read ~= 1000 + ws_MB, revealing ws_size.
        float sig = 1000.0f + (float)(ws_size >> 20);
        signal_kernel<<<(out_size + 255) / 256, 256, 0, stream>>>(out, out_size, sig);
        return;
    }

    char* p = (char*)d_ws;
    auto alloc = [&](size_t bytes) {
        void* r = (void*)p;
        p += (bytes + 255) & ~(size_t)255;
        return r;
    };
    float* h = (float*)alloc((size_t)NN * H * 4);
    __half* ea = (__half*)alloc((size_t)NE * H * 2);
    float* agg = (float*)alloc((size_t)NN * H * 4);
    float* cntf = (float*)alloc((size_t)NN * 4);
    int* cnt = (int*)alloc((size_t)NN * 4);
    int* rstart = (int*)alloc((size_t)(NN + 1) * 4);
    int* fptr = (int*)alloc((size_t)NN * 4);
    int* elist = (int*)alloc((size_t)NE * 4);

    encoder_kernel<<<NN, 128, 0, stream>>>(x, enc_w, enc_b, enc_g, enc_bb, h);
    eenc_kernel<<<NE, 128, 0, stream>>>(eattr, eenc_w, eenc_b, ea);
    hipMemsetAsync(cnt, 0, (size_t)NN * 4, stream);
    count_kernel<<<(NE + 255) / 256, 256, 0, stream>>>(eidx + NE, cnt);
    scan_kernel<<<1, 1024, 0, stream>>>(cnt, rstart, cntf);
    init_fill_kernel<<<(NN + 255) / 256, 256, 0, stream>>>(rstart, fptr);
    fill_kernel<<<(NE + 255) / 256, 256, 0, stream>>>(eidx + NE, fptr, elist);

    for (int l = 0; l < NLAYER; l++) {
        mlp_fused<true><<<NE / 32, 256, 0, stream>>>(
            h, ea, nullptr, eidx,
            e_w1 + (size_t)l * THREE_H * TWO_H, e_b1 + (size_t)l * TWO_H,
            e_g1 + (size_t)l * TWO_H, e_bb1 + (size_t)l * TWO_H,
            e_w2 + (size_t)l * TWO_H * H, e_b2 + (size_t)l * H,
            e_g2 + (size_t)l * H, e_bb2 + (size_t)l * H,
            ea, NE);
        aggregate_kernel<<<NN, 128, 0, stream>>>(ea, elist, rstart, cntf, agg);
        mlp_fused<false><<<(NN + 31) / 32, 256, 0, stream>>>(
            h, nullptr, agg, nullptr,
            n_w1 + (size_t)l * TWO_H * TWO_H, n_b1 + (size_t)l * TWO_H,
            n_g1 + (size_t)l * TWO_H, n_bb1 + (size_t)l * TWO_H,
            n_w2 + (size_t)l * TWO_H * H, n_b2 + (size_t)l * H,
            n_g2 + (size_t)l * H, n_bb2 + (size_t)l * H,
            h, NN);
    }
    decoder_kernel<<<NN, 128, 0, stream>>>(h, dec_w1, dec_b1, dec_w2, dec_b2, out);
}

// Round 8
// 7114.937 us; speedup vs baseline: 3.5111x; 3.5111x over previous
//
#include <hip/hip_runtime.h>
#include <hip/hip_fp16.h>
#include <math.h>

#define NN 50000
#define NE 600000
#define H 128
#define TWO_H 256
#define THREE_H 384
#define NLAYER 10

typedef __attribute__((ext_vector_type(4))) float f32x4;
typedef __attribute__((ext_vector_type(8))) short s16x8;
typedef __attribute__((ext_vector_type(4))) short s16x4;

__device__ __forceinline__ float gelu_f(float x) {
    return 0.5f * x * (1.0f + erff(x * 0.70710678118654752f));
}

__device__ __forceinline__ unsigned short f2bf(float f) {
    union { float f; unsigned u; } c; c.f = f;
    unsigned r = (c.u + 0x7fffu + ((c.u >> 16) & 1u)) >> 16;
    return (unsigned short)r;
}

__device__ __forceinline__ float wave_reduce_add64(float v) {
#pragma unroll
    for (int m = 32; m >= 1; m >>= 1) v += __shfl_xor(v, m);
    return v;
}

__global__ void signal_kernel(float* __restrict__ out, int n, float val) {
    int i = blockIdx.x * blockDim.x + threadIdx.x;
    if (i < n) out[i] = val;
}

// ---------------- weight prep: fp32 [L][K][N] -> bf16 [L][N][K] ----------------
__global__ void transpose_cvt_kernel(const float* __restrict__ src,
                                     unsigned short* __restrict__ dst,
                                     int K, int N, int total) {
    int i = blockIdx.x * 256 + threadIdx.x;
    if (i >= total) return;
    int n = i % N;
    int lk = i / N;
    int k = lk % K;
    int l = lk / K;
    dst[((size_t)l * N + n) * K + k] = f2bf(src[i]);
}

// ---------------- encoder: h = GELU(LN(x @ enc_w + enc_b)) ----------------
__global__ __launch_bounds__(128) void encoder_kernel(
    const float* __restrict__ x, const float* __restrict__ w,
    const float* __restrict__ b, const float* __restrict__ g,
    const float* __restrict__ bb, float* __restrict__ h) {
    int n = blockIdx.x;
    int j = threadIdx.x;
    __shared__ float xs[3];
    __shared__ float2 red[2];
    if (j < 3) xs[j] = x[n * 3 + j];
    __syncthreads();
    float v = b[j] + xs[0] * w[j] + xs[1] * w[H + j] + xs[2] * w[2 * H + j];
    float s = v, sq = v * v;
    s = wave_reduce_add64(s);
    sq = wave_reduce_add64(sq);
    if ((j & 63) == 0) red[j >> 6] = make_float2(s, sq);
    __syncthreads();
    float ts = red[0].x + red[1].x;
    float tq = red[0].y + red[1].y;
    float m = ts * (1.0f / 128.0f);
    float var = tq * (1.0f / 128.0f) - m * m;
    float rs = rsqrtf(var + 1e-5f);
    h[(size_t)n * H + j] = gelu_f((v - m) * rs * g[j] + bb[j]);
}

// ---------------- edge encoder: ea = edge_attr @ eenc_w + eenc_b (fp16) ----------------
__global__ __launch_bounds__(128) void eenc_kernel(
    const float* __restrict__ attr, const float* __restrict__ w,
    const float* __restrict__ b, __half* __restrict__ ea) {
    int e = blockIdx.x;
    int j = threadIdx.x;
    __shared__ float as_[8];
    if (j < 8) as_[j] = attr[(size_t)e * 8 + j];
    __syncthreads();
    float v = b[j];
#pragma unroll
    for (int k = 0; k < 8; k++) v += as_[k] * w[k * H + j];
    ea[(size_t)e * H + j] = __float2half_rn(v);
}

__global__ void count_kernel(const int* __restrict__ col, int* __restrict__ cnt) {
    int i = blockIdx.x * blockDim.x + threadIdx.x;
    if (i < NE) atomicAdd(&cnt[col[i]], 1);
}

__global__ __launch_bounds__(1024) void scan_kernel(
    const int* __restrict__ cnt, int* __restrict__ rstart, float* __restrict__ cntf) {
    __shared__ int buf[1024];
    __shared__ int s_carry;
    int tid = threadIdx.x;
    if (tid == 0) s_carry = 0;
    __syncthreads();
    for (int base = 0; base < NN; base += 1024) {
        int i = base + tid;
        int v = (i < NN) ? cnt[i] : 0;
        buf[tid] = v;
        __syncthreads();
        for (int off = 1; off < 1024; off <<= 1) {
            int add = (tid >= off) ? buf[tid - off] : 0;
            __syncthreads();
            buf[tid] += add;
            __syncthreads();
        }
        int incl = buf[tid];
        int cv = s_carry;
        if (i < NN) {
            rstart[i] = cv + incl - v;
            cntf[i] = (float)(v > 1 ? v : 1);
        }
        __syncthreads();
        if (tid == 0) s_carry = cv + buf[1023];
        __syncthreads();
    }
    if (threadIdx.x == 0) rstart[NN] = s_carry;
}

__global__ void init_fill_kernel(const int* __restrict__ rstart, int* __restrict__ fptr) {
    int i = blockIdx.x * blockDim.x + threadIdx.x;
    if (i < NN) fptr[i] = rstart[i];
}

__global__ void fill_kernel(const int* __restrict__ col, int* __restrict__ fptr,
                            int* __restrict__ elist) {
    int i = blockIdx.x * blockDim.x + threadIdx.x;
    if (i < NE) {
        int c = col[i];
        int p = atomicAdd(&fptr[c], 1);
        elist[p] = i;
    }
}

// ---------------- CSR mean aggregation: fp16 ea -> bf16 agg ----------------
__global__ __launch_bounds__(128) void aggregate_kernel(
    const __half* __restrict__ ea, const int* __restrict__ elist,
    const int* __restrict__ rstart, const float* __restrict__ cntf,
    unsigned short* __restrict__ agg) {
    int n = blockIdx.x;
    int t = threadIdx.x;
    int s = rstart[n], e_end = rstart[n + 1];
    float sum = 0.0f;
    for (int p = s; p < e_end; ++p) {
        int e = elist[p];
        sum += __half2float(ea[(size_t)e * H + t]);
    }
    agg[(size_t)n * H + t] = f2bf(sum / cntf[n]);
}

// ---------------- fused MFMA MLP: resid += LN2(GELU(LN1(in@w1+b1))@w2+b2) ----------------
// 64 rows/block, 4 waves. Wave w: GEMM1 cols [w*64,w*64+64), GEMM2 cols [w*32,w*32+32).
// A staged bf16 in LDS [64][KIN+8]; weights pre-transposed bf16 [N][K] read from global (L2).
// LN via in-register 16-lane shfl partials + cross-wave LDS reduce.
// EDGE: in=[h[row]|h[col]|ea] K=384, resid=ea (fp16). NODE: in=[h|agg] K=256, resid=h (fp32).
template <bool EDGE>
__global__ __launch_bounds__(256, 2) void mlp_mfma(
    const float* h, __half* ea, const unsigned short* __restrict__ agg,
    const int* __restrict__ eidx,
    const unsigned short* __restrict__ w1T, const float* __restrict__ b1,
    const float* __restrict__ g1, const float* __restrict__ bb1,
    const unsigned short* __restrict__ w2T, const float* __restrict__ b2,
    const float* __restrict__ g2, const float* __restrict__ bb2,
    float* hout, int nrows) {
    constexpr int KIN = EDGE ? THREE_H : TWO_H;
    constexpr int ALD = KIN + 8;   // bf16 elems per row (pad 8 -> 2-way conflicts only)
    constexpr int ZLD = TWO_H + 8; // 264

    __shared__ __align__(16) short A_s[64 * ALD];
    __shared__ float2 red[64][4];
    short* z_s = A_s;  // z tile [64][264] aliases A_s (A dead before z written)

    const int t = threadIdx.x;
    const int wave = t >> 6;
    const int lane = t & 63;
    const int lanelo = lane & 15;
    const int grp = lane >> 4;
    const size_t r0 = (size_t)blockIdx.x * 64;

    // ---- stage A: gather + convert to bf16 ----
    {
        int r = t >> 2;      // 0..63
        int ph = t & 3;      // 4 threads interleave over k
        size_t row_g = r0 + r;
        const float* s0;
        const float* s1 = nullptr;
        const unsigned short* s2;
        if constexpr (EDGE) {
            int ri = eidx[row_g];
            int ci = eidx[NE + row_g];
            s0 = h + (size_t)ri * H;
            s1 = h + (size_t)ci * H;
            s2 = (const unsigned short*)ea + row_g * H;  // fp16 bits
        } else {
            size_t n = row_g < (size_t)nrows ? row_g : (size_t)(nrows - 1);
            s0 = h + n * H;
            s2 = agg + n * H;  // bf16 bits
        }
        short* arow = A_s + r * ALD;
        for (int k = ph * 4; k < KIN; k += 16) {
            s16x4 sv;
            if constexpr (EDGE) {
                if (k < H) {
                    float4 v = *(const float4*)(s0 + k);
                    sv[0] = (short)f2bf(v.x); sv[1] = (short)f2bf(v.y);
                    sv[2] = (short)f2bf(v.z); sv[3] = (short)f2bf(v.w);
                } else if (k < 2 * H) {
                    float4 v = *(const float4*)(s1 + (k - H));
                    sv[0] = (short)f2bf(v.x); sv[1] = (short)f2bf(v.y);
                    sv[2] = (short)f2bf(v.z); sv[3] = (short)f2bf(v.w);
                } else {
                    const __half2* q = (const __half2*)(s2 + (k - 2 * H));
                    float2 f0 = __half22float2(q[0]);
                    float2 f1 = __half22float2(q[1]);
                    sv[0] = (short)f2bf(f0.x); sv[1] = (short)f2bf(f0.y);
                    sv[2] = (short)f2bf(f1.x); sv[3] = (short)f2bf(f1.y);
                }
            } else {
                if (k < H) {
                    float4 v = *(const float4*)(s0 + k);
                    sv[0] = (short)f2bf(v.x); sv[1] = (short)f2bf(v.y);
                    sv[2] = (short)f2bf(v.z); sv[3] = (short)f2bf(v.w);
                } else {
                    sv = *(const s16x4*)((const short*)s2 + (k - H));
                }
            }
            *(s16x4*)(arow + k) = sv;
        }
    }
    __syncthreads();

    // ---- GEMM1: z[64][256] = A @ w1 ----
    f32x4 acc[4][4];
#pragma unroll
    for (int rt = 0; rt < 4; rt++)
#pragma unroll
        for (int ct = 0; ct < 4; ct++) acc[rt][ct] = (f32x4){0.f, 0.f, 0.f, 0.f};

    const int c1 = wave * 64 + lanelo;  // +ct*16
    for (int ks = 0; ks < KIN / 32; ++ks) {
        const int k0 = ks * 32 + grp * 8;
        s16x8 a[4], b[4];
#pragma unroll
        for (int rt = 0; rt < 4; rt++)
            a[rt] = *(const s16x8*)(A_s + (rt * 16 + lanelo) * ALD + k0);
#pragma unroll
        for (int ct = 0; ct < 4; ct++)
            b[ct] = *(const s16x8*)(w1T + (size_t)(c1 + ct * 16) * KIN + k0);
#pragma unroll
        for (int rt = 0; rt < 4; rt++)
#pragma unroll
            for (int ct = 0; ct < 4; ct++)
                acc[rt][ct] = __builtin_amdgcn_mfma_f32_16x16x32_bf16(
                    a[rt], b[ct], acc[rt][ct], 0, 0, 0);
    }

    // ---- LN1 partial sums (wave covers 64 cols; cross-wave via red) ----
    float b1c[4];
#pragma unroll
    for (int ct = 0; ct < 4; ct++) b1c[ct] = b1[c1 + ct * 16];
#pragma unroll
    for (int rt = 0; rt < 4; rt++)
#pragma unroll
        for (int i = 0; i < 4; i++) {
            float s = 0.f, q = 0.f;
#pragma unroll
            for (int ct = 0; ct < 4; ct++) {
                float z = acc[rt][ct][i] + b1c[ct];
                s += z; q += z * z;
            }
            s += __shfl_xor(s, 1); s += __shfl_xor(s, 2);
            s += __shfl_xor(s, 4); s += __shfl_xor(s, 8);
            q += __shfl_xor(q, 1); q += __shfl_xor(q, 2);
            q += __shfl_xor(q, 4); q += __shfl_xor(q, 8);
            if (lanelo == 0) red[rt * 16 + grp * 4 + i][wave] = make_float2(s, q);
        }
    __syncthreads();  // also fences: all waves done reading A_s -> z_s writes safe

    // ---- LN1 apply + GELU + write z bf16 ----
    {
        float g1c[4], bb1c[4];
#pragma unroll
        for (int ct = 0; ct < 4; ct++) { g1c[ct] = g1[c1 + ct * 16]; bb1c[ct] = bb1[c1 + ct * 16]; }
#pragma unroll
        for (int rt = 0; rt < 4; rt++)
#pragma unroll
            for (int i = 0; i < 4; i++) {
                int r = rt * 16 + grp * 4 + i;
                float2 p0 = red[r][0], p1 = red[r][1], p2 = red[r][2], p3 = red[r][3];
                float sum = p0.x + p1.x + p2.x + p3.x;
                float sq = p0.y + p1.y + p2.y + p3.y;
                float m = sum * (1.f / 256.f);
                float var = sq * (1.f / 256.f) - m * m;
                float rs = rsqrtf(var + 1e-5f);
#pragma unroll
                for (int ct = 0; ct < 4; ct++) {
                    float z = acc[rt][ct][i] + b1c[ct];
                    float v = (z - m) * rs * g1c[ct] + bb1c[ct];
                    z_s[r * ZLD + c1 + ct * 16] = (short)f2bf(gelu_f(v));
                }
            }
    }
    __syncthreads();

    // ---- GEMM2: d[64][128] = z @ w2 ----
    f32x4 acc2[4][2];
#pragma unroll
    for (int rt = 0; rt < 4; rt++)
#pragma unroll
        for (int ct = 0; ct < 2; ct++) acc2[rt][ct] = (f32x4){0.f, 0.f, 0.f, 0.f};

    const int c2 = wave * 32 + lanelo;  // +ct*16
    for (int ks = 0; ks < TWO_H / 32; ++ks) {
        const int k0 = ks * 32 + grp * 8;
        s16x8 a2[4], b2v[2];
#pragma unroll
        for (int rt = 0; rt < 4; rt++)
            a2[rt] = *(const s16x8*)(z_s + (rt * 16 + lanelo) * ZLD + k0);
#pragma unroll
        for (int ct = 0; ct < 2; ct++)
            b2v[ct] = *(const s16x8*)(w2T + (size_t)(c2 + ct * 16) * TWO_H + k0);
#pragma unroll
        for (int rt = 0; rt < 4; rt++)
#pragma unroll
            for (int ct = 0; ct < 2; ct++)
                acc2[rt][ct] = __builtin_amdgcn_mfma_f32_16x16x32_bf16(
                    a2[rt], b2v[ct], acc2[rt][ct], 0, 0, 0);
    }

    // ---- LN2 partials ----
    float b2c[2];
#pragma unroll
    for (int ct = 0; ct < 2; ct++) b2c[ct] = b2[c2 + ct * 16];
#pragma unroll
    for (int rt = 0; rt < 4; rt++)
#pragma unroll
        for (int i = 0; i < 4; i++) {
            float s = 0.f, q = 0.f;
#pragma unroll
            for (int ct = 0; ct < 2; ct++) {
                float z = acc2[rt][ct][i] + b2c[ct];
                s += z; q += z * z;
            }
            s += __shfl_xor(s, 1); s += __shfl_xor(s, 2);
            s += __shfl_xor(s, 4); s += __shfl_xor(s, 8);
            q += __shfl_xor(q, 1); q += __shfl_xor(q, 2);
            q += __shfl_xor(q, 4); q += __shfl_xor(q, 8);
            if (lanelo == 0) red[rt * 16 + grp * 4 + i][wave] = make_float2(s, q);
        }
    __syncthreads();

    // ---- LN2 apply + residual RMW ----
    {
        float g2c[2], bb2c[2];
#pragma unroll
        for (int ct = 0; ct < 2; ct++) { g2c[ct] = g2[c2 + ct * 16]; bb2c[ct] = bb2[c2 + ct * 16]; }
#pragma unroll
        for (int rt = 0; rt < 4; rt++)
#pragma unroll
            for (int i = 0; i < 4; i++) {
                int r = rt * 16 + grp * 4 + i;
                float2 p0 = red[r][0], p1 = red[r][1], p2 = red[r][2], p3 = red[r][3];
                float sum = p0.x + p1.x + p2.x + p3.x;
                float sq = p0.y + p1.y + p2.y + p3.y;
                float m = sum * (1.f / 128.f);
                float var = sq * (1.f / 128.f) - m * m;
                float rs = rsqrtf(var + 1e-5f);
                size_t rowg = r0 + r;
#pragma unroll
                for (int ct = 0; ct < 2; ct++) {
                    float z = acc2[rt][ct][i] + b2c[ct];
                    float d = (z - m) * rs * g2c[ct] + bb2c[ct];
                    size_t idx = rowg * H + (c2 + ct * 16);
                    if constexpr (EDGE) {
                        ea[idx] = __float2half_rn(__half2float(ea[idx]) + d);
                    } else {
                        if (rowg < (size_t)nrows) hout[idx] += d;
                    }
                }
            }
    }
}

// ---------------- decoder: out = GELU(h @ w1 + b1) @ w2 + b2 ----------------
__global__ __launch_bounds__(128) void decoder_kernel(
    const float* __restrict__ h, const float* __restrict__ w1,
    const float* __restrict__ b1, const float* __restrict__ w2,
    const float* __restrict__ b2, float* __restrict__ out) {
    int n = blockIdx.x;
    int j = threadIdx.x;
    __shared__ float hs[128];
    __shared__ float4 red[2];
    hs[j] = h[(size_t)n * H + j];
    __syncthreads();
    float t1 = b1[j];
#pragma unroll 8
    for (int k = 0; k < 128; k++) t1 += hs[k] * w1[k * H + j];
    t1 = gelu_f(t1);
    float4 w = *(const float4*)(w2 + j * 4);
    float4 p = make_float4(t1 * w.x, t1 * w.y, t1 * w.z, t1 * w.w);
#pragma unroll
    for (int m = 32; m >= 1; m >>= 1) {
        p.x += __shfl_xor(p.x, m);
        p.y += __shfl_xor(p.y, m);
        p.z += __shfl_xor(p.z, m);
        p.w += __shfl_xor(p.w, m);
    }
    if ((j & 63) == 0) red[j >> 6] = p;
    __syncthreads();
    if (j == 0) {
        out[(size_t)n * 4 + 0] = red[0].x + red[1].x + b2[0];
        out[(size_t)n * 4 + 1] = red[0].y + red[1].y + b2[1];
        out[(size_t)n * 4 + 2] = red[0].z + red[1].z + b2[2];
        out[(size_t)n * 4 + 3] = red[0].w + red[1].w + b2[3];
    }
}

extern "C" void kernel_launch(void* const* d_in, const int* in_sizes, int n_in,
                              void* d_out, int out_size, void* d_ws, size_t ws_size,
                              hipStream_t stream) {
    const float* x = (const float*)d_in[0];
    const int* eidx = (const int*)d_in[1];
    const float* eattr = (const float*)d_in[2];
    const float* enc_w = (const float*)d_in[3];
    const float* enc_b = (const float*)d_in[4];
    const float* enc_g = (const float*)d_in[5];
    const float* enc_bb = (const float*)d_in[6];
    const float* eenc_w = (const float*)d_in[7];
    const float* eenc_b = (const float*)d_in[8];
    const float* e_w1 = (const float*)d_in[9];
    const float* e_b1 = (const float*)d_in[10];
    const float* e_g1 = (const float*)d_in[11];
    const float* e_bb1 = (const float*)d_in[12];
    const float* e_w2 = (const float*)d_in[13];
    const float* e_b2 = (const float*)d_in[14];
    const float* e_g2 = (const float*)d_in[15];
    const float* e_bb2 = (const float*)d_in[16];
    const float* n_w1 = (const float*)d_in[17];
    const float* n_b1 = (const float*)d_in[18];
    const float* n_g1 = (const float*)d_in[19];
    const float* n_bb1 = (const float*)d_in[20];
    const float* n_w2 = (const float*)d_in[21];
    const float* n_b2 = (const float*)d_in[22];
    const float* n_g2 = (const float*)d_in[23];
    const float* n_bb2 = (const float*)d_in[24];
    const float* dec_w1 = (const float*)d_in[25];
    const float* dec_b1 = (const float*)d_in[26];
    const float* dec_w2 = (const float*)d_in[27];
    const float* dec_b2 = (const float*)d_in[28];
    float* out = (float*)d_out;
    (void)in_sizes; (void)n_in;

    auto AL = [](size_t b) { return (b + 255) & ~(size_t)255; };
    const size_t sz_h = AL((size_t)NN * H * 4);
    const size_t sz_ea = AL((size_t)NE * H * 2);
    const size_t sz_agg = AL((size_t)NN * H * 2);
    const size_t sz_cntf = AL((size_t)NN * 4);
    const size_t sz_cnt = AL((size_t)NN * 4);
    const size_t sz_rst = AL((size_t)(NN + 1) * 4);
    const size_t sz_fptr = AL((size_t)NN * 4);
    const size_t sz_elist = AL((size_t)NE * 4);
    const size_t sz_ew1 = AL((size_t)NLAYER * TWO_H * THREE_H * 2);
    const size_t sz_ew2 = AL((size_t)NLAYER * H * TWO_H * 2);
    const size_t sz_nw1 = AL((size_t)NLAYER * TWO_H * TWO_H * 2);
    const size_t sz_nw2 = AL((size_t)NLAYER * H * TWO_H * 2);
    const size_t need = sz_h + sz_ea + sz_agg + sz_cntf + sz_cnt + sz_rst +
                        sz_fptr + sz_elist + sz_ew1 + sz_ew2 + sz_nw1 + sz_nw2;

    if (ws_size < need) {
        float sig = 1000.0f + (float)(ws_size >> 20);
        signal_kernel<<<(out_size + 255) / 256, 256, 0, stream>>>(out, out_size, sig);
        return;
    }

    char* p = (char*)d_ws;
    auto alloc = [&](size_t bytes) { void* r = (void*)p; p += bytes; return r; };
    float* h = (float*)alloc(sz_h);
    __half* ea = (__half*)alloc(sz_ea);
    unsigned short* agg = (unsigned short*)alloc(sz_agg);
    float* cntf = (float*)alloc(sz_cntf);
    int* cnt = (int*)alloc(sz_cnt);
    int* rstart = (int*)alloc(sz_rst);
    int* fptr = (int*)alloc(sz_fptr);
    int* elist = (int*)alloc(sz_elist);
    unsigned short* ew1T = (unsigned short*)alloc(sz_ew1);
    unsigned short* ew2T = (unsigned short*)alloc(sz_ew2);
    unsigned short* nw1T = (unsigned short*)alloc(sz_nw1);
    unsigned short* nw2T = (unsigned short*)alloc(sz_nw2);

    // weight prep (bf16 + transpose to [N][K])
    {
        int tot;
        tot = NLAYER * THREE_H * TWO_H;
        transpose_cvt_kernel<<<(tot + 255) / 256, 256, 0, stream>>>(e_w1, ew1T, THREE_H, TWO_H, tot);
        tot = NLAYER * TWO_H * H;
        transpose_cvt_kernel<<<(tot + 255) / 256, 256, 0, stream>>>(e_w2, ew2T, TWO_H, H, tot);
        tot = NLAYER * TWO_H * TWO_H;
        transpose_cvt_kernel<<<(tot + 255) / 256, 256, 0, stream>>>(n_w1, nw1T, TWO_H, TWO_H, tot);
        tot = NLAYER * TWO_H * H;
        transpose_cvt_kernel<<<(tot + 255) / 256, 256, 0, stream>>>(n_w2, nw2T, TWO_H, H, tot);
    }

    encoder_kernel<<<NN, 128, 0, stream>>>(x, enc_w, enc_b, enc_g, enc_bb, h);
    eenc_kernel<<<NE, 128, 0, stream>>>(eattr, eenc_w, eenc_b, ea);
    hipMemsetAsync(cnt, 0, (size_t)NN * 4, stream);
    count_kernel<<<(NE + 255) / 256, 256, 0, stream>>>(eidx + NE, cnt);
    scan_kernel<<<1, 1024, 0, stream>>>(cnt, rstart, cntf);
    init_fill_kernel<<<(NN + 255) / 256, 256, 0, stream>>>(rstart, fptr);
    fill_kernel<<<(NE + 255) / 256, 256, 0, stream>>>(eidx + NE, fptr, elist);

    for (int l = 0; l < NLAYER; l++) {
        mlp_mfma<true><<<NE / 64, 256, 0, stream>>>(
            h, ea, nullptr, eidx,
            ew1T + (size_t)l * TWO_H * THREE_H, e_b1 + (size_t)l * TWO_H,
            e_g1 + (size_t)l * TWO_H, e_bb1 + (size_t)l * TWO_H,
            ew2T + (size_t)l * H * TWO_H, e_b2 + (size_t)l * H,
            e_g2 + (size_t)l * H, e_bb2 + (size_t)l * H,
            nullptr, NE);
        aggregate_kernel<<<NN, 128, 0, stream>>>(ea, elist, rstart, cntf, agg);
        mlp_mfma<false><<<(NN + 63) / 64, 256, 0, stream>>>(
            h, nullptr, agg, nullptr,
            nw1T + (size_t)l * TWO_H * TWO_H, n_b1 + (size_t)l * TWO_H,
            n_g1 + (size_t)l * TWO_H, n_bb1 + (size_t)l * TWO_H,
            nw2T + (size_t)l * H * TWO_H, n_b2 + (size_t)l * H,
            n_g2 + (size_t)l * H, n_bb2 + (size_t)l * H,
            h, NN);
    }
    decoder_kernel<<<NN, 128, 0, stream>>>(h, dec_w1, dec_b1, dec_w2, dec_b2, out);
}

// Round 9
// 5537.295 us; speedup vs baseline: 4.5115x; 1.2849x over previous
//
#include <hip/hip_runtime.h>
#include <hip/hip_fp16.h>
#include <math.h>

#define NN 50000
#define NE 600000
#define H 128
#define TWO_H 256
#define THREE_H 384
#define NLAYER 10

typedef __attribute__((ext_vector_type(4))) float f32x4;
typedef __attribute__((ext_vector_type(8))) short s16x8;
typedef _Float16 f16x8 __attribute__((ext_vector_type(8)));

__device__ __forceinline__ float gelu_f(float x) {
    return 0.5f * x * (1.0f + erff(x * 0.70710678118654752f));
}

// tanh-form GELU: max |err vs exact| ~3e-4, ~10 VALU ops (v_exp + v_rcp HW ops)
__device__ __forceinline__ float gelu_fast(float x) {
    float u = x * fmaf(0.044715f, x * x, 1.0f);
    float e = __expf(1.5957691216057308f * u);   // e^{2*sqrt(2/pi)*u}
    return x * (1.0f - __builtin_amdgcn_rcpf(e + 1.0f));
}

__device__ __forceinline__ float wave_reduce_add64(float v) {
#pragma unroll
    for (int m = 32; m >= 1; m >>= 1) v += __shfl_xor(v, m);
    return v;
}

__global__ void signal_kernel(float* __restrict__ out, int n, float val) {
    int i = blockIdx.x * blockDim.x + threadIdx.x;
    if (i < n) out[i] = val;
}

// ---------------- weight prep: fp32 [L][K][N] -> fp16 [L][N][K] ----------------
__global__ void transpose_cvt_kernel(const float* __restrict__ src,
                                     __half* __restrict__ dst,
                                     int K, int N, int total) {
    int i = blockIdx.x * 256 + threadIdx.x;
    if (i >= total) return;
    int n = i % N;
    int lk = i / N;
    int k = lk % K;
    int l = lk / K;
    dst[((size_t)l * N + n) * K + k] = __float2half_rn(src[i]);
}

// ---------------- encoder: h = GELU(LN(x @ enc_w + enc_b)) -> fp16 ----------------
__global__ __launch_bounds__(128) void encoder_kernel(
    const float* __restrict__ x, const float* __restrict__ w,
    const float* __restrict__ b, const float* __restrict__ g,
    const float* __restrict__ bb, __half* __restrict__ hh) {
    int n = blockIdx.x;
    int j = threadIdx.x;
    __shared__ float xs[3];
    __shared__ float2 red[2];
    if (j < 3) xs[j] = x[n * 3 + j];
    __syncthreads();
    float v = b[j] + xs[0] * w[j] + xs[1] * w[H + j] + xs[2] * w[2 * H + j];
    float s = v, sq = v * v;
    s = wave_reduce_add64(s);
    sq = wave_reduce_add64(sq);
    if ((j & 63) == 0) red[j >> 6] = make_float2(s, sq);
    __syncthreads();
    float ts = red[0].x + red[1].x;
    float tq = red[0].y + red[1].y;
    float m = ts * (1.0f / 128.0f);
    float var = tq * (1.0f / 128.0f) - m * m;
    float rs = rsqrtf(var + 1e-5f);
    hh[(size_t)n * H + j] = __float2half_rn(gelu_f((v - m) * rs * g[j] + bb[j]));
}

// ---------------- edge encoder: ea = edge_attr @ eenc_w + eenc_b (fp16) ----------------
__global__ __launch_bounds__(128) void eenc_kernel(
    const float* __restrict__ attr, const float* __restrict__ w,
    const float* __restrict__ b, __half* __restrict__ ea) {
    int e = blockIdx.x;
    int j = threadIdx.x;
    __shared__ float as_[8];
    if (j < 8) as_[j] = attr[(size_t)e * 8 + j];
    __syncthreads();
    float v = b[j];
#pragma unroll
    for (int k = 0; k < 8; k++) v += as_[k] * w[k * H + j];
    ea[(size_t)e * H + j] = __float2half_rn(v);
}

__global__ void count_kernel(const int* __restrict__ col, int* __restrict__ cnt) {
    int i = blockIdx.x * blockDim.x + threadIdx.x;
    if (i < NE) atomicAdd(&cnt[col[i]], 1);
}

__global__ __launch_bounds__(1024) void scan_kernel(
    const int* __restrict__ cnt, int* __restrict__ rstart, float* __restrict__ cntf) {
    __shared__ int buf[1024];
    __shared__ int s_carry;
    int tid = threadIdx.x;
    if (tid == 0) s_carry = 0;
    __syncthreads();
    for (int base = 0; base < NN; base += 1024) {
        int i = base + tid;
        int v = (i < NN) ? cnt[i] : 0;
        buf[tid] = v;
        __syncthreads();
        for (int off = 1; off < 1024; off <<= 1) {
            int add = (tid >= off) ? buf[tid - off] : 0;
            __syncthreads();
            buf[tid] += add;
            __syncthreads();
        }
        int incl = buf[tid];
        int cv = s_carry;
        if (i < NN) {
            rstart[i] = cv + incl - v;
            cntf[i] = (float)(v > 1 ? v : 1);
        }
        __syncthreads();
        if (tid == 0) s_carry = cv + buf[1023];
        __syncthreads();
    }
    if (threadIdx.x == 0) rstart[NN] = s_carry;
}

__global__ void init_fill_kernel(const int* __restrict__ rstart, int* __restrict__ fptr) {
    int i = blockIdx.x * blockDim.x + threadIdx.x;
    if (i < NN) fptr[i] = rstart[i];
}

__global__ void fill_kernel(const int* __restrict__ col, int* __restrict__ fptr,
                            int* __restrict__ elist) {
    int i = blockIdx.x * blockDim.x + threadIdx.x;
    if (i < NE) {
        int c = col[i];
        int p = atomicAdd(&fptr[c], 1);
        elist[p] = i;
    }
}

// ---------------- CSR mean aggregation: fp16 ea -> fp16 agg (fp32 accum) ----------------
__global__ __launch_bounds__(128) void aggregate_kernel(
    const __half* __restrict__ ea, const int* __restrict__ elist,
    const int* __restrict__ rstart, const float* __restrict__ cntf,
    __half* __restrict__ agg) {
    int n = blockIdx.x;
    int t = threadIdx.x;
    int s = rstart[n], e_end = rstart[n + 1];
    float sum = 0.0f;
    for (int p = s; p < e_end; ++p) {
        int e = elist[p];
        sum += __half2float(ea[(size_t)e * H + t]);
    }
    agg[(size_t)n * H + t] = __float2half_rn(sum / cntf[n]);
}

// ---------------- fused f16-MFMA MLP: resid += LN2(GELU(LN1(in@w1+b1))@w2+b2) ----------------
// 64 rows/block, 4 waves. Wave w: GEMM1 cols [w*64,+64), GEMM2 cols [w*32,+32).
// All operands fp16: staging = pure bit-copies (no conversions).
// EDGE: in=[hh[row]|hh[col]|ea] K=384, resid=ea. NODE: in=[hh|agg] K=256, resid=hh.
template <bool EDGE>
__global__ __launch_bounds__(256, 2) void mlp_mfma(
    __half* hh, __half* ea, const __half* __restrict__ agg,
    const int* __restrict__ eidx,
    const __half* __restrict__ w1T, const float* __restrict__ b1,
    const float* __restrict__ g1, const float* __restrict__ bb1,
    const __half* __restrict__ w2T, const float* __restrict__ b2,
    const float* __restrict__ g2, const float* __restrict__ bb2,
    int nrows) {
    constexpr int KIN = EDGE ? THREE_H : TWO_H;
    constexpr int ALD = KIN + 8;   // halves; odd word-stride -> conflict-free rows
    constexpr int ZLD = TWO_H + 8; // 264

    __shared__ __align__(16) short A_s[64 * ALD];
    __shared__ float2 red[64][4];
    short* z_s = A_s;  // z tile [64][264] aliases A_s (A dead before z written)

    const int t = threadIdx.x;
    const int wave = t >> 6;
    const int lane = t & 63;
    const int lanelo = lane & 15;
    const int grp = lane >> 4;
    const size_t r0 = (size_t)blockIdx.x * 64;

    // ---- stage A: pure fp16 bit-copies (16B each) ----
    {
        int r = t >> 2;      // 0..63
        int ph = t & 3;      // 4 threads interleave over k
        size_t row_g = r0 + r;
        const short* s0;
        const short* s1 = nullptr;
        const short* s2;
        if constexpr (EDGE) {
            int ri = eidx[row_g];
            int ci = eidx[NE + row_g];
            s0 = (const short*)hh + (size_t)ri * H;
            s1 = (const short*)hh + (size_t)ci * H;
            s2 = (const short*)ea + row_g * H;
        } else {
            size_t n = row_g < (size_t)nrows ? row_g : (size_t)(nrows - 1);
            s0 = (const short*)hh + n * H;
            s2 = (const short*)agg + n * H;
        }
        short* arow = A_s + r * ALD;
        for (int k = ph * 8; k < KIN; k += 32) {
            s16x8 sv;
            if constexpr (EDGE) {
                if (k < H) sv = *(const s16x8*)(s0 + k);
                else if (k < 2 * H) sv = *(const s16x8*)(s1 + (k - H));
                else sv = *(const s16x8*)(s2 + (k - 2 * H));
            } else {
                sv = (k < H) ? *(const s16x8*)(s0 + k) : *(const s16x8*)(s2 + (k - H));
            }
            *(s16x8*)(arow + k) = sv;
        }
    }
    __syncthreads();

    // ---- GEMM1: z[64][256] = A @ w1 ----
    f32x4 acc[4][4];
#pragma unroll
    for (int rt = 0; rt < 4; rt++)
#pragma unroll
        for (int ct = 0; ct < 4; ct++) acc[rt][ct] = (f32x4){0.f, 0.f, 0.f, 0.f};

    const int c1 = wave * 64 + lanelo;  // +ct*16
    for (int ks = 0; ks < KIN / 32; ++ks) {
        const int k0 = ks * 32 + grp * 8;
        f16x8 a[4], b[4];
#pragma unroll
        for (int rt = 0; rt < 4; rt++)
            a[rt] = *(const f16x8*)(const void*)(A_s + (rt * 16 + lanelo) * ALD + k0);
#pragma unroll
        for (int ct = 0; ct < 4; ct++)
            b[ct] = *(const f16x8*)(const void*)(w1T + (size_t)(c1 + ct * 16) * KIN + k0);
#pragma unroll
        for (int rt = 0; rt < 4; rt++)
#pragma unroll
            for (int ct = 0; ct < 4; ct++)
                acc[rt][ct] = __builtin_amdgcn_mfma_f32_16x16x32_f16(
                    a[rt], b[ct], acc[rt][ct], 0, 0, 0);
    }

    // ---- fold bias into acc, LN1 partials ----
#pragma unroll
    for (int ct = 0; ct < 4; ct++) {
        float bc = b1[c1 + ct * 16];
#pragma unroll
        for (int rt = 0; rt < 4; rt++)
#pragma unroll
            for (int i = 0; i < 4; i++) acc[rt][ct][i] += bc;
    }
#pragma unroll
    for (int rt = 0; rt < 4; rt++)
#pragma unroll
        for (int i = 0; i < 4; i++) {
            float s = 0.f, q = 0.f;
#pragma unroll
            for (int ct = 0; ct < 4; ct++) {
                float z = acc[rt][ct][i];
                s += z; q += z * z;
            }
            s += __shfl_xor(s, 1); s += __shfl_xor(s, 2);
            s += __shfl_xor(s, 4); s += __shfl_xor(s, 8);
            q += __shfl_xor(q, 1); q += __shfl_xor(q, 2);
            q += __shfl_xor(q, 4); q += __shfl_xor(q, 8);
            if (lanelo == 0) red[rt * 16 + grp * 4 + i][wave] = make_float2(s, q);
        }
    __syncthreads();  // fences A_s reads too -> z_s writes safe

    // ---- LN1 apply + fast GELU + write z fp16 ----
    {
        float g1c[4], bb1c[4];
#pragma unroll
        for (int ct = 0; ct < 4; ct++) { g1c[ct] = g1[c1 + ct * 16]; bb1c[ct] = bb1[c1 + ct * 16]; }
#pragma unroll
        for (int rt = 0; rt < 4; rt++)
#pragma unroll
            for (int i = 0; i < 4; i++) {
                int r = rt * 16 + grp * 4 + i;
                float2 p0 = red[r][0], p1 = red[r][1], p2 = red[r][2], p3 = red[r][3];
                float sum = p0.x + p1.x + p2.x + p3.x;
                float sq = p0.y + p1.y + p2.y + p3.y;
                float m = sum * (1.f / 256.f);
                float var = sq * (1.f / 256.f) - m * m;
                float rs = rsqrtf(var + 1e-5f);
#pragma unroll
                for (int ct = 0; ct < 4; ct++) {
                    float v = (acc[rt][ct][i] - m) * rs * g1c[ct] + bb1c[ct];
                    __half hv = __float2half_rn(gelu_fast(v));
                    z_s[r * ZLD + c1 + ct * 16] = __half_as_short(hv);
                }
            }
    }
    __syncthreads();

    // ---- GEMM2: d[64][128] = z @ w2 ----
    f32x4 acc2[4][2];
#pragma unroll
    for (int rt = 0; rt < 4; rt++)
#pragma unroll
        for (int ct = 0; ct < 2; ct++) acc2[rt][ct] = (f32x4){0.f, 0.f, 0.f, 0.f};

    const int c2 = wave * 32 + lanelo;  // +ct*16
    for (int ks = 0; ks < TWO_H / 32; ++ks) {
        const int k0 = ks * 32 + grp * 8;
        f16x8 a2[4], b2v[2];
#pragma unroll
        for (int rt = 0; rt < 4; rt++)
            a2[rt] = *(const f16x8*)(const void*)(z_s + (rt * 16 + lanelo) * ZLD + k0);
#pragma unroll
        for (int ct = 0; ct < 2; ct++)
            b2v[ct] = *(const f16x8*)(const void*)(w2T + (size_t)(c2 + ct * 16) * TWO_H + k0);
#pragma unroll
        for (int rt = 0; rt < 4; rt++)
#pragma unroll
            for (int ct = 0; ct < 2; ct++)
                acc2[rt][ct] = __builtin_amdgcn_mfma_f32_16x16x32_f16(
                    a2[rt], b2v[ct], acc2[rt][ct], 0, 0, 0);
    }

    // ---- fold bias, LN2 partials ----
#pragma unroll
    for (int ct = 0; ct < 2; ct++) {
        float bc = b2[c2 + ct * 16];
#pragma unroll
        for (int rt = 0; rt < 4; rt++)
#pragma unroll
            for (int i = 0; i < 4; i++) acc2[rt][ct][i] += bc;
    }
#pragma unroll
    for (int rt = 0; rt < 4; rt++)
#pragma unroll
        for (int i = 0; i < 4; i++) {
            float s = 0.f, q = 0.f;
#pragma unroll
            for (int ct = 0; ct < 2; ct++) {
                float z = acc2[rt][ct][i];
                s += z; q += z * z;
            }
            s += __shfl_xor(s, 1); s += __shfl_xor(s, 2);
            s += __shfl_xor(s, 4); s += __shfl_xor(s, 8);
            q += __shfl_xor(q, 1); q += __shfl_xor(q, 2);
            q += __shfl_xor(q, 4); q += __shfl_xor(q, 8);
            if (lanelo == 0) red[rt * 16 + grp * 4 + i][wave] = make_float2(s, q);
        }
    __syncthreads();

    // ---- LN2 apply + residual RMW (fp16 state) ----
    {
        float g2c[2], bb2c[2];
#pragma unroll
        for (int ct = 0; ct < 2; ct++) { g2c[ct] = g2[c2 + ct * 16]; bb2c[ct] = bb2[c2 + ct * 16]; }
#pragma unroll
        for (int rt = 0; rt < 4; rt++)
#pragma unroll
            for (int i = 0; i < 4; i++) {
                int r = rt * 16 + grp * 4 + i;
                float2 p0 = red[r][0], p1 = red[r][1], p2 = red[r][2], p3 = red[r][3];
                float sum = p0.x + p1.x + p2.x + p3.x;
                float sq = p0.y + p1.y + p2.y + p3.y;
                float m = sum * (1.f / 128.f);
                float var = sq * (1.f / 128.f) - m * m;
                float rs = rsqrtf(var + 1e-5f);
                size_t rowg = r0 + r;
#pragma unroll
                for (int ct = 0; ct < 2; ct++) {
                    float d = (acc2[rt][ct][i] - m) * rs * g2c[ct] + bb2c[ct];
                    size_t idx = rowg * H + (c2 + ct * 16);
                    if constexpr (EDGE) {
                        ea[idx] = __float2half_rn(__half2float(ea[idx]) + d);
                    } else {
                        if (rowg < (size_t)nrows)
                            hh[idx] = __float2half_rn(__half2float(hh[idx]) + d);
                    }
                }
            }
    }
}

// ---------------- decoder: out = GELU(h @ w1 + b1) @ w2 + b2 ----------------
__global__ __launch_bounds__(128) void decoder_kernel(
    const __half* __restrict__ hh, const float* __restrict__ w1,
    const float* __restrict__ b1, const float* __restrict__ w2,
    const float* __restrict__ b2, float* __restrict__ out) {
    int n = blockIdx.x;
    int j = threadIdx.x;
    __shared__ float hs[128];
    __shared__ float4 red[2];
    hs[j] = __half2float(hh[(size_t)n * H + j]);
    __syncthreads();
    float t1 = b1[j];
#pragma unroll 8
    for (int k = 0; k < 128; k++) t1 += hs[k] * w1[k * H + j];
    t1 = gelu_f(t1);
    float4 w = *(const float4*)(w2 + j * 4);
    float4 p = make_float4(t1 * w.x, t1 * w.y, t1 * w.z, t1 * w.w);
#pragma unroll
    for (int m = 32; m >= 1; m >>= 1) {
        p.x += __shfl_xor(p.x, m);
        p.y += __shfl_xor(p.y, m);
        p.z += __shfl_xor(p.z, m);
        p.w += __shfl_xor(p.w, m);
    }
    if ((j & 63) == 0) red[j >> 6] = p;
    __syncthreads();
    if (j == 0) {
        out[(size_t)n * 4 + 0] = red[0].x + red[1].x + b2[0];
        out[(size_t)n * 4 + 1] = red[0].y + red[1].y + b2[1];
        out[(size_t)n * 4 + 2] = red[0].z + red[1].z + b2[2];
        out[(size_t)n * 4 + 3] = red[0].w + red[1].w + b2[3];
    }
}

extern "C" void kernel_launch(void* const* d_in, const int* in_sizes, int n_in,
                              void* d_out, int out_size, void* d_ws, size_t ws_size,
                              hipStream_t stream) {
    const float* x = (const float*)d_in[0];
    const int* eidx = (const int*)d_in[1];
    const float* eattr = (const float*)d_in[2];
    const float* enc_w = (const float*)d_in[3];
    const float* enc_b = (const float*)d_in[4];
    const float* enc_g = (const float*)d_in[5];
    const float* enc_bb = (const float*)d_in[6];
    const float* eenc_w = (const float*)d_in[7];
    const float* eenc_b = (const float*)d_in[8];
    const float* e_w1 = (const float*)d_in[9];
    const float* e_b1 = (const float*)d_in[10];
    const float* e_g1 = (const float*)d_in[11];
    const float* e_bb1 = (const float*)d_in[12];
    const float* e_w2 = (const float*)d_in[13];
    const float* e_b2 = (const float*)d_in[14];
    const float* e_g2 = (const float*)d_in[15];
    const float* e_bb2 = (const float*)d_in[16];
    const float* n_w1 = (const float*)d_in[17];
    const float* n_b1 = (const float*)d_in[18];
    const float* n_g1 = (const float*)d_in[19];
    const float* n_bb1 = (const float*)d_in[20];
    const float* n_w2 = (const float*)d_in[21];
    const float* n_b2 = (const float*)d_in[22];
    const float* n_g2 = (const float*)d_in[23];
    const float* n_bb2 = (const float*)d_in[24];
    const float* dec_w1 = (const float*)d_in[25];
    const float* dec_b1 = (const float*)d_in[26];
    const float* dec_w2 = (const float*)d_in[27];
    const float* dec_b2 = (const float*)d_in[28];
    float* out = (float*)d_out;
    (void)in_sizes; (void)n_in;

    auto AL = [](size_t b) { return (b + 255) & ~(size_t)255; };
    const size_t sz_hh = AL((size_t)NN * H * 2);
    const size_t sz_ea = AL((size_t)NE * H * 2);
    const size_t sz_agg = AL((size_t)NN * H * 2);
    const size_t sz_cntf = AL((size_t)NN * 4);
    const size_t sz_cnt = AL((size_t)NN * 4);
    const size_t sz_rst = AL((size_t)(NN + 1) * 4);
    const size_t sz_fptr = AL((size_t)NN * 4);
    const size_t sz_elist = AL((size_t)NE * 4);
    const size_t sz_ew1 = AL((size_t)NLAYER * TWO_H * THREE_H * 2);
    const size_t sz_ew2 = AL((size_t)NLAYER * H * TWO_H * 2);
    const size_t sz_nw1 = AL((size_t)NLAYER * TWO_H * TWO_H * 2);
    const size_t sz_nw2 = AL((size_t)NLAYER * H * TWO_H * 2);
    const size_t need = sz_hh + sz_ea + sz_agg + sz_cntf + sz_cnt + sz_rst +
                        sz_fptr + sz_elist + sz_ew1 + sz_ew2 + sz_nw1 + sz_nw2;

    if (ws_size < need) {
        float sig = 1000.0f + (float)(ws_size >> 20);
        signal_kernel<<<(out_size + 255) / 256, 256, 0, stream>>>(out, out_size, sig);
        return;
    }

    char* p = (char*)d_ws;
    auto alloc = [&](size_t bytes) { void* r = (void*)p; p += bytes; return r; };
    __half* hh = (__half*)alloc(sz_hh);
    __half* ea = (__half*)alloc(sz_ea);
    __half* agg = (__half*)alloc(sz_agg);
    float* cntf = (float*)alloc(sz_cntf);
    int* cnt = (int*)alloc(sz_cnt);
    int* rstart = (int*)alloc(sz_rst);
    int* fptr = (int*)alloc(sz_fptr);
    int* elist = (int*)alloc(sz_elist);
    __half* ew1T = (__half*)alloc(sz_ew1);
    __half* ew2T = (__half*)alloc(sz_ew2);
    __half* nw1T = (__half*)alloc(sz_nw1);
    __half* nw2T = (__half*)alloc(sz_nw2);

    // weight prep (fp16 + transpose to [N][K])
    {
        int tot;
        tot = NLAYER * THREE_H * TWO_H;
        transpose_cvt_kernel<<<(tot + 255) / 256, 256, 0, stream>>>(e_w1, ew1T, THREE_H, TWO_H, tot);
        tot = NLAYER * TWO_H * H;
        transpose_cvt_kernel<<<(tot + 255) / 256, 256, 0, stream>>>(e_w2, ew2T, TWO_H, H, tot);
        tot = NLAYER * TWO_H * TWO_H;
        transpose_cvt_kernel<<<(tot + 255) / 256, 256, 0, stream>>>(n_w1, nw1T, TWO_H, TWO_H, tot);
        tot = NLAYER * TWO_H * H;
        transpose_cvt_kernel<<<(tot + 255) / 256, 256, 0, stream>>>(n_w2, nw2T, TWO_H, H, tot);
    }

    encoder_kernel<<<NN, 128, 0, stream>>>(x, enc_w, enc_b, enc_g, enc_bb, hh);
    eenc_kernel<<<NE, 128, 0, stream>>>(eattr, eenc_w, eenc_b, ea);
    hipMemsetAsync(cnt, 0, (size_t)NN * 4, stream);
    count_kernel<<<(NE + 255) / 256, 256, 0, stream>>>(eidx + NE, cnt);
    scan_kernel<<<1, 1024, 0, stream>>>(cnt, rstart, cntf);
    init_fill_kernel<<<(NN + 255) / 256, 256, 0, stream>>>(rstart, fptr);
    fill_kernel<<<(NE + 255) / 256, 256, 0, stream>>>(eidx + NE, fptr, elist);

    for (int l = 0; l < NLAYER; l++) {
        mlp_mfma<true><<<NE / 64, 256, 0, stream>>>(
            hh, ea, nullptr, eidx,
            ew1T + (size_t)l * TWO_H * THREE_H, e_b1 + (size_t)l * TWO_H,
            e_g1 + (size_t)l * TWO_H, e_bb1 + (size_t)l * TWO_H,
            ew2T + (size_t)l * H * TWO_H, e_b2 + (size_t)l * H,
            e_g2 + (size_t)l * H, e_bb2 + (size_t)l * H,
            NE);
        aggregate_kernel<<<NN, 128, 0, stream>>>(ea, elist, rstart, cntf, agg);
        mlp_mfma<false><<<(NN + 63) / 64, 256, 0, stream>>>(
            hh, nullptr, agg, nullptr,
            nw1T + (size_t)l * TWO_H * TWO_H, n_b1 + (size_t)l * TWO_H,
            n_g1 + (size_t)l * TWO_H, n_bb1 + (size_t)l * TWO_H,
            nw2T + (size_t)l * H * TWO_H, n_b2 + (size_t)l * H,
            n_g2 + (size_t)l * H, n_bb2 + (size_t)l * H,
            NN);
    }
    decoder_kernel<<<NN, 128, 0, stream>>>(hh, dec_w1, dec_b1, dec_w2, dec_b2, out);
}